// Round 5
// baseline (229.496 us; speedup 1.0000x reference)
//
#include <hip/hip_runtime.h>
#include <hip/hip_bf16.h>
#include <math.h>

// ADC LUT-quantization kernel, round 4.
// out = floor(interp1d(lut_x, lut_y, clip(x/8*lut_x[-1], ...)) * 256/max(lut_y)) * 8/256
//
// R4 changes vs R3 (208.3us = 5.15 TB/s, 82% of 6.29 TB/s copy ceiling):
//  - no per-element idx clamp: guess_scale shrunk by (1-2^-18) so v=in_max
//    maps below idx_hi+1; trunc-toward-zero covers the >=0 side. Chords are
//    continuous at knots, so +/-1 cell near a knot changes y only by fp eps.
//  - 8x strided unroll: all 8 dwordx4 loads in flight before compute/store.
//  - nt loads+stores (touch-once streams), affine LDS table (A,B) float2.

#define LUT_MAX 4096
#define BLOCK 512

typedef float f32x4 __attribute__((ext_vector_type(4)));

__global__ __launch_bounds__(BLOCK) void adc_fused_kernel(
    const float* __restrict__ x,
    const float* __restrict__ lut_x,
    const float* __restrict__ lut_y,
    float* __restrict__ out,
    long long n, int lutN)
{
    __shared__ float2 sAB[LUT_MAX];      // (A_i, B_i) per segment
    __shared__ float wmax[BLOCK / 64];

    const int tid = threadIdx.x;

    // ---- phase 1: out_max = max(lut_y) (block-redundant, trivial cost) ----
    float lm = -INFINITY;
    for (int i = tid; i < lutN; i += BLOCK)
        lm = fmaxf(lm, lut_y[i]);
    #pragma unroll
    for (int o = 32; o > 0; o >>= 1)
        lm = fmaxf(lm, __shfl_down(lm, o, 64));
    if ((tid & 63) == 0) wmax[tid >> 6] = lm;
    __syncthreads();
    float out_max = wmax[0];
    #pragma unroll
    for (int w = 1; w < BLOCK / 64; ++w)
        out_max = fmaxf(out_max, wmax[w]);

    const float scale  = 256.0f / out_max;           // full_scale / adc_out_max
    const float in_min = lut_x[0];
    const float in_max = lut_x[lutN - 1];
    // shrink so (in_max - in_min)*guess_scale < lutN-1 strictly -> no idx clamp
    const float guess_scale = ((float)(lutN - 1) / (in_max - in_min))
                              * (1.0f - 3.8147e-6f /* 2^-18 */);
    const float guess_bias  = -in_min * guess_scale;

    // ---- phase 2: build fused affine table (re-read lut from L2) ----
    for (int i = tid; i < lutN - 1; i += BLOCK) {
        float x0 = lut_x[i], x1 = lut_x[i + 1];
        float y0 = lut_y[i], y1 = lut_y[i + 1];
        float slope = (y1 - y0) / (x1 - x0);
        sAB[i] = make_float2(scale * (y0 - x0 * slope), scale * slope);
    }
    __syncthreads();

    const float xscale = 0.125f * in_max;  // x * (1/8) * lut_x[-1]

    auto quant = [&](float xin) -> float {
        float v  = fminf(fmaxf(xin * xscale, in_min), in_max);  // v_med3
        int  idx = (int)fmaf(v, guess_scale, guess_bias);       // no clamp
        float2 ab = sAB[idx];
        return floorf(fmaf(v, ab.y, ab.x)) * 0.03125f;          // * 8/256
    };

    auto quant4 = [&](f32x4 a) -> f32x4 {
        f32x4 r;
        r.x = quant(a.x); r.y = quant(a.y); r.z = quant(a.z); r.w = quant(a.w);
        return r;
    };

    // ---- main loop: grid-stride f32x4, 8x strided unroll, nontemporal ----
    const long long n4 = n >> 2;
    const f32x4* __restrict__ x4 = (const f32x4*)x;
    f32x4* __restrict__ o4 = (f32x4*)out;
    const long long gstride = (long long)gridDim.x * BLOCK;
    long long i = (long long)blockIdx.x * BLOCK + tid;

    for (; i + 7 * gstride < n4; i += 8 * gstride) {
        f32x4 a0 = __builtin_nontemporal_load(&x4[i]);
        f32x4 a1 = __builtin_nontemporal_load(&x4[i + gstride]);
        f32x4 a2 = __builtin_nontemporal_load(&x4[i + 2 * gstride]);
        f32x4 a3 = __builtin_nontemporal_load(&x4[i + 3 * gstride]);
        f32x4 a4 = __builtin_nontemporal_load(&x4[i + 4 * gstride]);
        f32x4 a5 = __builtin_nontemporal_load(&x4[i + 5 * gstride]);
        f32x4 a6 = __builtin_nontemporal_load(&x4[i + 6 * gstride]);
        f32x4 a7 = __builtin_nontemporal_load(&x4[i + 7 * gstride]);
        __builtin_nontemporal_store(quant4(a0), &o4[i]);
        __builtin_nontemporal_store(quant4(a1), &o4[i + gstride]);
        __builtin_nontemporal_store(quant4(a2), &o4[i + 2 * gstride]);
        __builtin_nontemporal_store(quant4(a3), &o4[i + 3 * gstride]);
        __builtin_nontemporal_store(quant4(a4), &o4[i + 4 * gstride]);
        __builtin_nontemporal_store(quant4(a5), &o4[i + 5 * gstride]);
        __builtin_nontemporal_store(quant4(a6), &o4[i + 6 * gstride]);
        __builtin_nontemporal_store(quant4(a7), &o4[i + 7 * gstride]);
    }
    for (; i < n4; i += gstride) {
        f32x4 a = __builtin_nontemporal_load(&x4[i]);
        __builtin_nontemporal_store(quant4(a), &o4[i]);
    }

    // ---- scalar tail (n not multiple of 4) ----
    for (long long j = (n4 << 2) + (long long)blockIdx.x * BLOCK + tid;
         j < n; j += gstride) {
        out[j] = quant(x[j]);
    }
}

extern "C" void kernel_launch(void* const* d_in, const int* in_sizes, int n_in,
                              void* d_out, int out_size, void* d_ws, size_t ws_size,
                              hipStream_t stream) {
    const float* x     = (const float*)d_in[0];
    const float* lut_x = (const float*)d_in[1];
    const float* lut_y = (const float*)d_in[2];
    float* out = (float*)d_out;

    const long long n = (long long)out_size;
    const int lutN = in_sizes[1];

    long long n4 = n >> 2;
    long long want = (n4 + BLOCK - 1) / BLOCK;
    int blocks = (int)(want < 1024 ? want : 1024);  // 4 blocks/CU (LDS-limited)
    if (blocks < 1) blocks = 1;

    adc_fused_kernel<<<blocks, BLOCK, 0, stream>>>(x, lut_x, lut_y, out, n, lutN);
}

// Round 6
// 208.906 us; speedup vs baseline: 1.0986x; 1.0986x over previous
//
#include <hip/hip_runtime.h>
#include <hip/hip_bf16.h>
#include <math.h>

// ADC LUT-quantization kernel, round 5 (revert R4's 8x unroll, keep no-clamp).
// out = floor(interp1d(lut_x, lut_y, clip(x/8*lut_x[-1], ...)) * 256/max(lut_y)) * 8/256
//
// R4 post-mortem: 8x unroll crossed the 64-VGPR occupancy cliff (32->16
// waves/CU at 4 blocks/CU x 512 thr) -> 229us. R3's 4x unroll = 208us.
// R5 = R3 structure + clamp-free index guess:
//  - guess_scale shrunk by (1-2^-18) so v=in_max maps below lutN-1;
//    trunc-toward-zero covers >=0. Chords continuous at knots -> +/-1 cell
//    near a knot changes y only by fp eps (<< 1 ADC code).
//  - 4x strided unroll, nt loads/stores, affine (A,B) float2 LDS table.

#define LUT_MAX 4096
#define BLOCK 512

typedef float f32x4 __attribute__((ext_vector_type(4)));

__global__ __launch_bounds__(BLOCK) void adc_fused_kernel(
    const float* __restrict__ x,
    const float* __restrict__ lut_x,
    const float* __restrict__ lut_y,
    float* __restrict__ out,
    long long n, int lutN)
{
    __shared__ float2 sAB[LUT_MAX];      // (A_i, B_i) per segment
    __shared__ float wmax[BLOCK / 64];

    const int tid = threadIdx.x;

    // ---- phase 1: out_max = max(lut_y) (block-redundant, trivial cost) ----
    float lm = -INFINITY;
    for (int i = tid; i < lutN; i += BLOCK)
        lm = fmaxf(lm, lut_y[i]);
    #pragma unroll
    for (int o = 32; o > 0; o >>= 1)
        lm = fmaxf(lm, __shfl_down(lm, o, 64));
    if ((tid & 63) == 0) wmax[tid >> 6] = lm;
    __syncthreads();
    float out_max = wmax[0];
    #pragma unroll
    for (int w = 1; w < BLOCK / 64; ++w)
        out_max = fmaxf(out_max, wmax[w]);

    const float scale  = 256.0f / out_max;           // full_scale / adc_out_max
    const float in_min = lut_x[0];
    const float in_max = lut_x[lutN - 1];
    // shrink so (in_max - in_min)*guess_scale < lutN-1 strictly -> no idx clamp
    const float guess_scale = ((float)(lutN - 1) / (in_max - in_min))
                              * (1.0f - 3.8147e-6f /* ~2^-18 */);
    const float guess_bias  = -in_min * guess_scale;

    // ---- phase 2: build fused affine table (re-read lut from L2) ----
    for (int i = tid; i < lutN - 1; i += BLOCK) {
        float x0 = lut_x[i], x1 = lut_x[i + 1];
        float y0 = lut_y[i], y1 = lut_y[i + 1];
        float slope = (y1 - y0) / (x1 - x0);
        sAB[i] = make_float2(scale * (y0 - x0 * slope), scale * slope);
    }
    __syncthreads();

    const float xscale = 0.125f * in_max;  // x * (1/8) * lut_x[-1]

    auto quant = [&](float xin) -> float {
        float v  = fminf(fmaxf(xin * xscale, in_min), in_max);  // v_med3
        int  idx = (int)fmaf(v, guess_scale, guess_bias);       // no clamp
        float2 ab = sAB[idx];
        return floorf(fmaf(v, ab.y, ab.x)) * 0.03125f;          // * 8/256
    };

    auto quant4 = [&](f32x4 a) -> f32x4 {
        f32x4 r;
        r.x = quant(a.x); r.y = quant(a.y); r.z = quant(a.z); r.w = quant(a.w);
        return r;
    };

    // ---- main loop: grid-stride f32x4, 4x strided unroll, nontemporal ----
    const long long n4 = n >> 2;
    const f32x4* __restrict__ x4 = (const f32x4*)x;
    f32x4* __restrict__ o4 = (f32x4*)out;
    const long long gstride = (long long)gridDim.x * BLOCK;
    long long i = (long long)blockIdx.x * BLOCK + tid;

    for (; i + 3 * gstride < n4; i += 4 * gstride) {
        f32x4 a0 = __builtin_nontemporal_load(&x4[i]);
        f32x4 a1 = __builtin_nontemporal_load(&x4[i + gstride]);
        f32x4 a2 = __builtin_nontemporal_load(&x4[i + 2 * gstride]);
        f32x4 a3 = __builtin_nontemporal_load(&x4[i + 3 * gstride]);
        f32x4 r0 = quant4(a0);
        f32x4 r1 = quant4(a1);
        f32x4 r2 = quant4(a2);
        f32x4 r3 = quant4(a3);
        __builtin_nontemporal_store(r0, &o4[i]);
        __builtin_nontemporal_store(r1, &o4[i + gstride]);
        __builtin_nontemporal_store(r2, &o4[i + 2 * gstride]);
        __builtin_nontemporal_store(r3, &o4[i + 3 * gstride]);
    }
    for (; i < n4; i += gstride) {
        f32x4 a = __builtin_nontemporal_load(&x4[i]);
        __builtin_nontemporal_store(quant4(a), &o4[i]);
    }

    // ---- scalar tail (n not multiple of 4) ----
    for (long long j = (n4 << 2) + (long long)blockIdx.x * BLOCK + tid;
         j < n; j += gstride) {
        out[j] = quant(x[j]);
    }
}

extern "C" void kernel_launch(void* const* d_in, const int* in_sizes, int n_in,
                              void* d_out, int out_size, void* d_ws, size_t ws_size,
                              hipStream_t stream) {
    const float* x     = (const float*)d_in[0];
    const float* lut_x = (const float*)d_in[1];
    const float* lut_y = (const float*)d_in[2];
    float* out = (float*)d_out;

    const long long n = (long long)out_size;
    const int lutN = in_sizes[1];

    long long n4 = n >> 2;
    long long want = (n4 + BLOCK - 1) / BLOCK;
    int blocks = (int)(want < 1024 ? want : 1024);  // 4 blocks/CU (LDS-limited)
    if (blocks < 1) blocks = 1;

    adc_fused_kernel<<<blocks, BLOCK, 0, stream>>>(x, lut_x, lut_y, out, n, lutN);
}